// Round 12
// baseline (54.916 us; speedup 1.0000x reference)
//
#include <hip/hip_runtime.h>

#define IMG_H 256
#define IMG_W 256
#define TW 64
#define TH 8
#define SC 72            // vertical-task cols: global cols c0-4 .. c0+67 (need -3..66)

typedef float v2f __attribute__((ext_vector_type(2)));

// per-row low-3-bit rotation: uniform bank-granule spread for b128 writes and
// reads. Validated R6/R7/R8: SQ_LDS_BANK_CONFLICT ~0 (stride-72-float4 family).
__device__ __forceinline__ int rotc(int r, int c) { return (c & ~7) | ((c + r) & 7); }

// Gaussian 7-tap, f64-derived f32 constants (matches numpy f32 recipe to ~1e-7 rel)
#define G0 0.03663285f
#define G1 0.11128076f
#define G2 0.21674532f
#define G3 0.27068216f

// Fused SSIM — R12: 128-thread blocks, 64x8 tile.
//  vertical:  72 tasks (1 col each; tid<72): 14 input rows -> 8 output rows.
//             Load redundancy 1.97/px (was 2.81, -30% VMEM); no spill tasks;
//             vertical wall = 1 pass (was 2). 3-tier edge paths (R11).
//  horizontal: 128 threads x (1 row x 4 cols); 10 b128 LDS reads; packed 7-tap;
//             SSIM map; 2-wave reduction. One main barrier; 2-wave convoy
//             (was 4); LDS 9.2KB -> occupancy ceiling 16 blocks/CU (thread-cap).
__global__ __launch_bounds__(128) void ssim_tile_kernel(
    const float* __restrict__ x, const float* __restrict__ y,
    float* __restrict__ partial) {
    __shared__ float4 vs[TH][SC];    // 9216 B
    __shared__ float  wsum[2];

    const int tid = threadIdx.x;
    const int bx = blockIdx.x, by = blockIdx.y, plane = blockIdx.z;
    const int r0 = by * TH, c0 = bx * TW;
    const size_t base = (size_t)plane * (IMG_H * IMG_W);
    const float g[7] = {G0, G1, G2, G3, G2, G1, G0};

    v2f g2[7];
    #pragma unroll
    for (int d = 0; d < 7; ++d) { g2[d].x = g[d]; g2[d].y = g[d]; }

    const bool rows_ok = (by >= 1) & (by <= 30);   // rows r0-3..r0+10 all in-bounds
    const bool cols_ok = (bx == 1) | (bx == 2);    // cols c0-4..c0+67 all in-bounds

    // ---------------- Vertical pass: global -> registers -> vs ----------------
    if (tid < SC) {
        const int c = tid;
        const int gc = c0 - 4 + c;
        const int rstart = r0 - 3;                 // 14 input rows rstart..rstart+13

        v2f aA[8], aB[8];
        #pragma unroll
        for (int o = 0; o < 8; ++o) { aA[o] = (v2f)0.f; aB[o] = (v2f)0.f; }

        if (rows_ok & cols_ok) {
            // tier1: constant row offsets, no clamps/selects
            const float* px = x + base + (size_t)rstart * IMG_W + gc;
            const float* py = y + base + (size_t)rstart * IMG_W + gc;
            #pragma unroll
            for (int t = 0; t < 14; ++t) {
                const float xv = px[t * IMG_W];
                const float yv = py[t * IMG_W];
                v2f ina; ina.x = xv; ina.y = yv;
                v2f inb; inb.x = fmaf(xv, xv, yv * yv); inb.y = xv * yv;
                #pragma unroll
                for (int o = 0; o < 8; ++o) {
                    const int dy = t - o;
                    if (dy >= 0 && dy < 7) {
                        aA[o] = __builtin_elementwise_fma(g2[dy], ina, aA[o]);
                        aB[o] = __builtin_elementwise_fma(g2[dy], inb, aB[o]);
                    }
                }
            }
        } else if (rows_ok) {
            // tier2: rows in-bounds, column clamp hoisted (1 mask-mul per value)
            const int  gcc = gc < 0 ? 0 : (gc > IMG_W - 1 ? IMG_W - 1 : gc);
            const float mc = ((unsigned)gc < IMG_W) ? 1.f : 0.f;
            const float* px = x + base + (size_t)rstart * IMG_W + gcc;
            const float* py = y + base + (size_t)rstart * IMG_W + gcc;
            #pragma unroll
            for (int t = 0; t < 14; ++t) {
                const float xv = px[t * IMG_W] * mc;
                const float yv = py[t * IMG_W] * mc;
                v2f ina; ina.x = xv; ina.y = yv;
                v2f inb; inb.x = fmaf(xv, xv, yv * yv); inb.y = xv * yv;
                #pragma unroll
                for (int o = 0; o < 8; ++o) {
                    const int dy = t - o;
                    if (dy >= 0 && dy < 7) {
                        aA[o] = __builtin_elementwise_fma(g2[dy], ina, aA[o]);
                        aB[o] = __builtin_elementwise_fma(g2[dy], inb, aB[o]);
                    }
                }
            }
        } else {
            // tier3: full clamp (by = 0 or 31 only, 6.25% of blocks)
            const bool ok_c = ((unsigned)gc < IMG_W);
            const int  gcc  = gc < 0 ? 0 : (gc > IMG_W - 1 ? IMG_W - 1 : gc);
            #pragma unroll
            for (int t = 0; t < 14; ++t) {
                const int gr  = rstart + t;
                const bool ok = ok_c & ((unsigned)gr < IMG_H);
                const int grc = gr < 0 ? 0 : (gr > IMG_H - 1 ? IMG_H - 1 : gr);
                const size_t idx = base + ((size_t)grc << 8) + gcc;
                float xv = x[idx], yv = y[idx];
                xv = ok ? xv : 0.f;
                yv = ok ? yv : 0.f;
                v2f ina; ina.x = xv; ina.y = yv;
                v2f inb; inb.x = fmaf(xv, xv, yv * yv); inb.y = xv * yv;
                #pragma unroll
                for (int o = 0; o < 8; ++o) {
                    const int dy = t - o;
                    if (dy >= 0 && dy < 7) {
                        aA[o] = __builtin_elementwise_fma(g2[dy], ina, aA[o]);
                        aB[o] = __builtin_elementwise_fma(g2[dy], inb, aB[o]);
                    }
                }
            }
        }
        #pragma unroll
        for (int o = 0; o < 8; ++o) {
            vs[o][rotc(o, c)] = make_float4(aA[o].x, aA[o].y, aB[o].x, aB[o].y);
        }
    }

    __syncthreads();

    // ---------------- Horizontal pass + SSIM ----------------
    const int R = tid & 7;               // out row 0..7
    const int m = tid >> 3;              // col group 0..15 -> cols 4m..4m+3

    v2f wa[10], wb[10];
    #pragma unroll
    for (int j = 0; j < 10; ++j) {
        float4 w = vs[R][rotc(R, 4 * m + j + 1)];   // vs col cc = actual col cc-4
        wa[j].x = w.x; wa[j].y = w.y;
        wb[j].x = w.z; wb[j].y = w.w;
    }

    const float c1 = 0.01f * 0.01f;
    const float c2 = 0.03f * 0.03f;
    float acc = 0.f;
    #pragma unroll
    for (int o = 0; o < 4; ++o) {
        v2f sab = (v2f)0.f, szw = (v2f)0.f;
        #pragma unroll
        for (int dx = 0; dx < 7; ++dx) {
            sab = __builtin_elementwise_fma(g2[dx], wa[o + dx], sab);
            szw = __builtin_elementwise_fma(g2[dx], wb[o + dx], szw);
        }
        const float sx = sab.x, sy = sab.y, szz = szw.x, sxy2 = szw.y;
        const float mu1s = sx * sx;
        const float mu2s = sy * sy;
        const float mu12 = sx * sy;
        const float s12  = sxy2 - mu12;          // sigma12
        const float ssum = szz - mu1s - mu2s;    // sigma1_sq + sigma2_sq
        const float num  = fmaf(2.f, mu12, c1) * fmaf(2.f, s12, c2);
        const float den  = (mu1s + mu2s + c1) * (ssum + c2);
        float rcp = __builtin_amdgcn_rcpf(den);
        rcp = rcp * (2.f - den * rcp);           // 1 Newton step (rel err ~1e-7)
        acc = fmaf(num, rcp, acc);
    }

    // ---------------- Block reduction (2 waves) ----------------
    #pragma unroll
    for (int off = 32; off > 0; off >>= 1)
        acc += __shfl_down(acc, off, 64);

    const int wave = tid >> 6;
    const int lane = tid & 63;
    if (lane == 0) wsum[wave] = acc;
    __syncthreads();
    if (tid == 0) {
        partial[((size_t)plane * 128) + by * 4 + bx] = wsum[0] + wsum[1];
    }
}

// Deterministic final reduction: single block, 1024 threads, double accumulation.
__global__ __launch_bounds__(1024) void ssim_reduce_kernel(
    const float4* __restrict__ p, float* __restrict__ out,
    int n4, double inv_count) {
    double a = 0.0;
    for (int i = threadIdx.x; i < n4; i += 1024) {
        float4 v = p[i];
        a += (double)v.x + (double)v.y + (double)v.z + (double)v.w;
    }
    #pragma unroll
    for (int off = 32; off > 0; off >>= 1)
        a += __shfl_down(a, off, 64);
    __shared__ double sd[16];
    const int wave = threadIdx.x >> 6;
    const int lane = threadIdx.x & 63;
    if (lane == 0) sd[wave] = a;
    __syncthreads();
    if (threadIdx.x == 0) {
        double t = 0.0;
        #pragma unroll
        for (int w = 0; w < 16; w++) t += sd[w];
        out[0] = (float)(t * inv_count);
    }
}

extern "C" void kernel_launch(void* const* d_in, const int* in_sizes, int n_in,
                              void* d_out, int out_size, void* d_ws, size_t ws_size,
                              hipStream_t stream) {
    const float* x = (const float*)d_in[0];
    const float* y = (const float*)d_in[1];
    float* out = (float*)d_out;
    float* partial = (float*)d_ws;

    const int total = in_sizes[0];                 // 12,582,912
    const int planes = total / (IMG_H * IMG_W);    // 192
    const int tiles_r = IMG_H / TH;                // 32
    const int tiles_c = IMG_W / TW;                // 4
    const int n_partial = planes * tiles_r * tiles_c;  // 24576

    dim3 grid(tiles_c, tiles_r, planes);
    ssim_tile_kernel<<<grid, dim3(128), 0, stream>>>(x, y, partial);

    ssim_reduce_kernel<<<1, 1024, 0, stream>>>((const float4*)partial, out,
                                               n_partial / 4, 1.0 / (double)total);
}

// Round 13
// 52.499 us; speedup vs baseline: 1.0460x; 1.0460x over previous
//
#include <hip/hip_runtime.h>

#define IMG_H 256
#define IMG_W 256
#define TW 64
#define TH 16
#define SC 72            // vertical-task cols: global cols c0-4 .. c0+67 (need -3..66)

typedef float v2f __attribute__((ext_vector_type(2)));

// per-row low-3-bit rotation: uniform bank-granule spread for b128 writes and
// reads. Validated R6/R7/R8: SQ_LDS_BANK_CONFLICT ~0 (stride-72-float4, TH=16).
__device__ __forceinline__ int rotc(int r, int c) { return (c & ~7) | ((c + r) & 7); }

// Gaussian 7-tap, f64-derived f32 constants (matches numpy f32 recipe to ~1e-7 rel)
#define G0 0.03663285f
#define G1 0.11128076f
#define G2 0.21674532f
#define G3 0.27068216f

// Fused SSIM — R13 = R8 shell + float2 vertical tasks (2 adjacent cols/task):
//  vertical:  144 tasks (4 row-groups x 36 col-pairs), one per thread (tid<144,
//             no wave-0 double-duty). 10 float2 loads x2 images per task
//             (VMEM inst halved vs R8, fully coalesced); serial tap chain
//             unchanged (10 iters), ILP doubled. Interior fast path; edge
//             blocks take the full-clamp scalar path (R11: tiering ~free).
//  horizontal: unchanged R8: 1 thread = 1 out-row x 4 cols; 10 b128 LDS reads;
//             packed 7-tap; SSIM map; block reduction. One main barrier.
__global__ __launch_bounds__(256) void ssim_tile_kernel(
    const float* __restrict__ x, const float* __restrict__ y,
    float* __restrict__ partial) {
    __shared__ float4 vs[TH][SC];    // 18432 B -> 8 blocks/CU
    __shared__ float  wsum[4];

    const int tid = threadIdx.x;
    const int bx = blockIdx.x, by = blockIdx.y, plane = blockIdx.z;
    const int r0 = by * TH, c0 = bx * TW;
    const size_t base = (size_t)plane * (IMG_H * IMG_W);
    const float g[7] = {G0, G1, G2, G3, G2, G1, G0};

    v2f g2[7];
    #pragma unroll
    for (int d = 0; d < 7; ++d) { g2[d].x = g[d]; g2[d].y = g[d]; }

    // uniform per-block: all vertical-task loads in-bounds?
    const bool fast = ((bx == 1) | (bx == 2)) & (by >= 1) & (by <= 14);

    // ---------------- Vertical pass: global -> registers -> vs ----------------
    if (tid < 144) {
        const int a = tid / 36;          // row-group 0..3
        const int p = tid - a * 36;      // col-pair 0..35
        const int cl = 2 * p;            // local cols cl, cl+1
        const int gc0 = c0 - 4 + cl;     // global col of first (even, 8B-aligned)
        const int rstart = r0 - 3 + 4 * a;

        v2f aA[2][4], aB[2][4];
        #pragma unroll
        for (int j = 0; j < 2; ++j)
            #pragma unroll
            for (int o = 0; o < 4; ++o) { aA[j][o] = (v2f)0.f; aB[j][o] = (v2f)0.f; }

        if (fast) {
            const float* px = x + base + (size_t)rstart * IMG_W + gc0;
            const float* py = y + base + (size_t)rstart * IMG_W + gc0;
            #pragma unroll
            for (int t = 0; t < 10; ++t) {
                const float2 xv2 = *(const float2*)(px + t * IMG_W);
                const float2 yv2 = *(const float2*)(py + t * IMG_W);
                #pragma unroll
                for (int j = 0; j < 2; ++j) {
                    const float xv = j ? xv2.y : xv2.x;
                    const float yv = j ? yv2.y : yv2.x;
                    v2f ina; ina.x = xv; ina.y = yv;
                    v2f inb; inb.x = fmaf(xv, xv, yv * yv); inb.y = xv * yv;
                    #pragma unroll
                    for (int o = 0; o < 4; ++o) {
                        const int dy = t - o;
                        if (dy >= 0 && dy < 7) {
                            aA[j][o] = __builtin_elementwise_fma(g2[dy], ina, aA[j][o]);
                            aB[j][o] = __builtin_elementwise_fma(g2[dy], inb, aB[j][o]);
                        }
                    }
                }
            }
        } else {
            // edge blocks: full clamp path (scalar loads)
            #pragma unroll
            for (int t = 0; t < 10; ++t) {
                const int gr  = rstart + t;
                const bool okr = ((unsigned)gr < IMG_H);
                const int grc = gr < 0 ? 0 : (gr > IMG_H - 1 ? IMG_H - 1 : gr);
                #pragma unroll
                for (int j = 0; j < 2; ++j) {
                    const int gc = gc0 + j;
                    const bool ok = okr & ((unsigned)gc < IMG_W);
                    const int gcc = gc < 0 ? 0 : (gc > IMG_W - 1 ? IMG_W - 1 : gc);
                    const size_t idx = base + ((size_t)grc << 8) + gcc;
                    float xv = x[idx], yv = y[idx];
                    xv = ok ? xv : 0.f;
                    yv = ok ? yv : 0.f;
                    v2f ina; ina.x = xv; ina.y = yv;
                    v2f inb; inb.x = fmaf(xv, xv, yv * yv); inb.y = xv * yv;
                    #pragma unroll
                    for (int o = 0; o < 4; ++o) {
                        const int dy = t - o;
                        if (dy >= 0 && dy < 7) {
                            aA[j][o] = __builtin_elementwise_fma(g2[dy], ina, aA[j][o]);
                            aB[j][o] = __builtin_elementwise_fma(g2[dy], inb, aB[j][o]);
                        }
                    }
                }
            }
        }
        #pragma unroll
        for (int o = 0; o < 4; ++o) {
            const int R = 4 * a + o;
            #pragma unroll
            for (int j = 0; j < 2; ++j) {
                vs[R][rotc(R, cl + j)] =
                    make_float4(aA[j][o].x, aA[j][o].y, aB[j][o].x, aB[j][o].y);
            }
        }
    }

    __syncthreads();

    // ---------------- Horizontal pass + SSIM ----------------
    const int R = 4 * (tid >> 6) + (tid & 3);
    const int m = (tid >> 2) & 15;       // cols 4m..4m+3

    v2f wa[10], wb[10];
    #pragma unroll
    for (int j = 0; j < 10; ++j) {
        float4 w = vs[R][rotc(R, 4 * m + j + 1)];   // vs col cc = actual col cc-4
        wa[j].x = w.x; wa[j].y = w.y;
        wb[j].x = w.z; wb[j].y = w.w;
    }

    const float c1 = 0.01f * 0.01f;
    const float c2 = 0.03f * 0.03f;
    float acc = 0.f;
    #pragma unroll
    for (int o = 0; o < 4; ++o) {
        v2f sab = (v2f)0.f, szw = (v2f)0.f;
        #pragma unroll
        for (int dx = 0; dx < 7; ++dx) {
            sab = __builtin_elementwise_fma(g2[dx], wa[o + dx], sab);
            szw = __builtin_elementwise_fma(g2[dx], wb[o + dx], szw);
        }
        const float sx = sab.x, sy = sab.y, szz = szw.x, sxy2 = szw.y;
        const float mu1s = sx * sx;
        const float mu2s = sy * sy;
        const float mu12 = sx * sy;
        const float s12  = sxy2 - mu12;          // sigma12
        const float ssum = szz - mu1s - mu2s;    // sigma1_sq + sigma2_sq
        const float num  = fmaf(2.f, mu12, c1) * fmaf(2.f, s12, c2);
        const float den  = (mu1s + mu2s + c1) * (ssum + c2);
        float rcp = __builtin_amdgcn_rcpf(den);
        rcp = rcp * (2.f - den * rcp);           // 1 Newton step (rel err ~1e-7)
        acc = fmaf(num, rcp, acc);
    }

    // ---------------- Block reduction ----------------
    #pragma unroll
    for (int off = 32; off > 0; off >>= 1)
        acc += __shfl_down(acc, off, 64);

    const int wave = tid >> 6;
    const int lane = tid & 63;
    if (lane == 0) wsum[wave] = acc;
    __syncthreads();
    if (tid == 0) {
        float t = wsum[0] + wsum[1] + wsum[2] + wsum[3];
        partial[((size_t)blockIdx.z * 64) + blockIdx.y * 4 + blockIdx.x] = t;
    }
}

// Deterministic final reduction: single block, 1024 threads, double accumulation.
__global__ __launch_bounds__(1024) void ssim_reduce_kernel(
    const float4* __restrict__ p, float* __restrict__ out,
    int n4, double inv_count) {
    double a = 0.0;
    for (int i = threadIdx.x; i < n4; i += 1024) {
        float4 v = p[i];
        a += (double)v.x + (double)v.y + (double)v.z + (double)v.w;
    }
    #pragma unroll
    for (int off = 32; off > 0; off >>= 1)
        a += __shfl_down(a, off, 64);
    __shared__ double sd[16];
    const int wave = threadIdx.x >> 6;
    const int lane = threadIdx.x & 63;
    if (lane == 0) sd[wave] = a;
    __syncthreads();
    if (threadIdx.x == 0) {
        double t = 0.0;
        #pragma unroll
        for (int w = 0; w < 16; w++) t += sd[w];
        out[0] = (float)(t * inv_count);
    }
}

extern "C" void kernel_launch(void* const* d_in, const int* in_sizes, int n_in,
                              void* d_out, int out_size, void* d_ws, size_t ws_size,
                              hipStream_t stream) {
    const float* x = (const float*)d_in[0];
    const float* y = (const float*)d_in[1];
    float* out = (float*)d_out;
    float* partial = (float*)d_ws;

    const int total = in_sizes[0];                 // 12,582,912
    const int planes = total / (IMG_H * IMG_W);    // 192
    const int tiles_r = IMG_H / TH;                // 16
    const int tiles_c = IMG_W / TW;                // 4
    const int n_partial = planes * tiles_r * tiles_c;  // 12288

    dim3 grid(tiles_c, tiles_r, planes);
    ssim_tile_kernel<<<grid, dim3(256), 0, stream>>>(x, y, partial);

    ssim_reduce_kernel<<<1, 1024, 0, stream>>>((const float4*)partial, out,
                                               n_partial / 4, 1.0 / (double)total);
}

// Round 14
// 45.319 us; speedup vs baseline: 1.2118x; 1.1584x over previous
//
#include <hip/hip_runtime.h>

#define IMG_H 256
#define IMG_W 256
#define TW 64
#define TH 16
#define SC 72            // vertical-task cols: global cols c0-4 .. c0+67 (need -3..66)

typedef float v2f __attribute__((ext_vector_type(2)));

// per-row low-3-bit rotation: uniform bank-granule spread for b128 writes and
// reads. Validated R6/R7/R8: SQ_LDS_BANK_CONFLICT ~0 (stride-72-float4, TH=16).
__device__ __forceinline__ int rotc(int r, int c) { return (c & ~7) | ((c + r) & 7); }

// Gaussian 7-tap, f64-derived f32 constants (matches numpy f32 recipe to ~1e-7 rel)
#define G0 0.03663285f
#define G1 0.11128076f
#define G2 0.21674532f
#define G3 0.27068216f

// Fused SSIM — FINAL (revert to R8, the measured optimum of the design space):
//  R9-R13 record: every topology change off this configuration regressed
//  (320-thr balance +4us, 8-row groups +4.4us, 64x8 tile +9.4us, col-pairs
//  +7us) and edge-tier micro-surgery nulled (R11). This exact kernel: 45.5us.
//
//  vertical:  288 tasks (4 row-groups x 72 cols) read x,y directly from global
//             (coalesced; halo re-reads are L1/L2 hits — R7-validated).
//             Fields packed as pairs (x,y),(x^2+y^2,x*y) -> v_pk_fma_f32
//             (R8-validated). Interior blocks (44%) take a clamp-free path
//             with compile-time row offsets. Wave-0 carries the 32 spill
//             tasks (R9: removing this gains nothing — hidden by 8 blk/CU).
//  horizontal: 1 thread = 1 out-row x 4 cols; 10 b128 LDS reads (conflict-free
//             via rotc swizzle); packed 7-tap; SSIM map (4-field algebra,
//             fast rcp + 1 Newton); block reduction. One main barrier.
__global__ __launch_bounds__(256) void ssim_tile_kernel(
    const float* __restrict__ x, const float* __restrict__ y,
    float* __restrict__ partial) {
    __shared__ float4 vs[TH][SC];    // 18432 B -> 8 blocks/CU (thread-capped)
    __shared__ float  wsum[4];

    const int tid = threadIdx.x;
    const int bx = blockIdx.x, by = blockIdx.y, plane = blockIdx.z;
    const int r0 = by * TH, c0 = bx * TW;
    const size_t base = (size_t)plane * (IMG_H * IMG_W);
    const float g[7] = {G0, G1, G2, G3, G2, G1, G0};

    v2f g2[7];
    #pragma unroll
    for (int d = 0; d < 7; ++d) { g2[d].x = g[d]; g2[d].y = g[d]; }

    // uniform per-block: all vertical-task loads in-bounds?
    const bool fast = ((bx == 1) | (bx == 2)) & (by >= 1) & (by <= 14);

    // ---------------- Vertical pass: global -> registers -> vs ----------------
    auto vtask = [&](int a, int c) {
        const int gc = c0 - 4 + c;
        const int rstart = r0 - 3 + 4 * a;

        float xr[10], yr[10];
        if (fast) {
            // all in-bounds: constant row offsets, no clamps/selects
            const float* px = x + base + (size_t)rstart * IMG_W + gc;
            const float* py = y + base + (size_t)rstart * IMG_W + gc;
            #pragma unroll
            for (int t = 0; t < 10; ++t) {
                xr[t] = px[t * IMG_W];
                yr[t] = py[t * IMG_W];
            }
        } else {
            const bool ok_c = ((unsigned)gc < IMG_W);
            const int  gcc  = gc < 0 ? 0 : (gc > IMG_W - 1 ? IMG_W - 1 : gc);
            #pragma unroll
            for (int t = 0; t < 10; ++t) {
                const int gr  = rstart + t;
                const bool ok = ok_c & ((unsigned)gr < IMG_H);
                const int grc = gr < 0 ? 0 : (gr > IMG_H - 1 ? IMG_H - 1 : gr);
                const size_t idx = base + ((size_t)grc << 8) + gcc;
                float xv = x[idx], yv = y[idx];
                xr[t] = ok ? xv : 0.f;
                yr[t] = ok ? yv : 0.f;
            }
        }

        v2f aA[4], aB[4];
        #pragma unroll
        for (int o = 0; o < 4; ++o) { aA[o] = (v2f)0.f; aB[o] = (v2f)0.f; }

        #pragma unroll
        for (int t = 0; t < 10; ++t) {
            const float xv = xr[t], yv = yr[t];
            v2f ina; ina.x = xv; ina.y = yv;
            v2f inb; inb.x = fmaf(xv, xv, yv * yv); inb.y = xv * yv;
            #pragma unroll
            for (int o = 0; o < 4; ++o) {
                const int dy = t - o;
                if (dy >= 0 && dy < 7) {
                    aA[o] = __builtin_elementwise_fma(g2[dy], ina, aA[o]);
                    aB[o] = __builtin_elementwise_fma(g2[dy], inb, aB[o]);
                }
            }
        }
        #pragma unroll
        for (int o = 0; o < 4; ++o) {
            const int R = 4 * a + o;
            vs[R][rotc(R, c)] = make_float4(aA[o].x, aA[o].y, aB[o].x, aB[o].y);
        }
    };

    vtask(tid >> 6, tid & 63);                     // tasks (a, c=0..63)
    if (tid < 32) vtask(tid >> 3, 64 + (tid & 7)); // tasks (a, c=64..71), wave 0

    __syncthreads();

    // ---------------- Horizontal pass + SSIM ----------------
    const int R = 4 * (tid >> 6) + (tid & 3);
    const int m = (tid >> 2) & 15;       // cols 4m..4m+3

    v2f wa[10], wb[10];
    #pragma unroll
    for (int j = 0; j < 10; ++j) {
        float4 w = vs[R][rotc(R, 4 * m + j + 1)];   // vs col cc = actual col cc-4
        wa[j].x = w.x; wa[j].y = w.y;
        wb[j].x = w.z; wb[j].y = w.w;
    }

    const float c1 = 0.01f * 0.01f;
    const float c2 = 0.03f * 0.03f;
    float acc = 0.f;
    #pragma unroll
    for (int o = 0; o < 4; ++o) {
        v2f sab = (v2f)0.f, szw = (v2f)0.f;
        #pragma unroll
        for (int dx = 0; dx < 7; ++dx) {
            sab = __builtin_elementwise_fma(g2[dx], wa[o + dx], sab);
            szw = __builtin_elementwise_fma(g2[dx], wb[o + dx], szw);
        }
        const float sx = sab.x, sy = sab.y, szz = szw.x, sxy2 = szw.y;
        const float mu1s = sx * sx;
        const float mu2s = sy * sy;
        const float mu12 = sx * sy;
        const float s12  = sxy2 - mu12;          // sigma12
        const float ssum = szz - mu1s - mu2s;    // sigma1_sq + sigma2_sq
        const float num  = fmaf(2.f, mu12, c1) * fmaf(2.f, s12, c2);
        const float den  = (mu1s + mu2s + c1) * (ssum + c2);
        float rcp = __builtin_amdgcn_rcpf(den);
        rcp = rcp * (2.f - den * rcp);           // 1 Newton step (rel err ~1e-7)
        acc = fmaf(num, rcp, acc);
    }

    // ---------------- Block reduction ----------------
    #pragma unroll
    for (int off = 32; off > 0; off >>= 1)
        acc += __shfl_down(acc, off, 64);

    const int wave = tid >> 6;
    const int lane = tid & 63;
    if (lane == 0) wsum[wave] = acc;
    __syncthreads();
    if (tid == 0) {
        float t = wsum[0] + wsum[1] + wsum[2] + wsum[3];
        partial[((size_t)blockIdx.z * 64) + blockIdx.y * 4 + blockIdx.x] = t;
    }
}

// Deterministic final reduction: single block, 1024 threads, double accumulation.
__global__ __launch_bounds__(1024) void ssim_reduce_kernel(
    const float4* __restrict__ p, float* __restrict__ out,
    int n4, double inv_count) {
    double a = 0.0;
    for (int i = threadIdx.x; i < n4; i += 1024) {
        float4 v = p[i];
        a += (double)v.x + (double)v.y + (double)v.z + (double)v.w;
    }
    #pragma unroll
    for (int off = 32; off > 0; off >>= 1)
        a += __shfl_down(a, off, 64);
    __shared__ double sd[16];
    const int wave = threadIdx.x >> 6;
    const int lane = threadIdx.x & 63;
    if (lane == 0) sd[wave] = a;
    __syncthreads();
    if (threadIdx.x == 0) {
        double t = 0.0;
        #pragma unroll
        for (int w = 0; w < 16; w++) t += sd[w];
        out[0] = (float)(t * inv_count);
    }
}

extern "C" void kernel_launch(void* const* d_in, const int* in_sizes, int n_in,
                              void* d_out, int out_size, void* d_ws, size_t ws_size,
                              hipStream_t stream) {
    const float* x = (const float*)d_in[0];
    const float* y = (const float*)d_in[1];
    float* out = (float*)d_out;
    float* partial = (float*)d_ws;

    const int total = in_sizes[0];                 // 12,582,912
    const int planes = total / (IMG_H * IMG_W);    // 192
    const int tiles_r = IMG_H / TH;                // 16
    const int tiles_c = IMG_W / TW;                // 4
    const int n_partial = planes * tiles_r * tiles_c;  // 12288

    dim3 grid(tiles_c, tiles_r, planes);
    ssim_tile_kernel<<<grid, dim3(256), 0, stream>>>(x, y, partial);

    ssim_reduce_kernel<<<1, 1024, 0, stream>>>((const float4*)partial, out,
                                               n_partial / 4, 1.0 / (double)total);
}